// Round 11
// baseline (1088.351 us; speedup 1.0000x reference)
//
#include <hip/hip_runtime.h>

// ---------------------------------------------------------------------------
// SparseConvUNet forward, round 11: DENSE formulation. All activations stored
// dense bf16 (garbage at inactive, masked by consumers). Convs are dense
// implicit GEMMs: flat-shifted coalesced A loads, per-wave register weights
// (tap-split x4), 4-way LDS reduce, fused BN stats. Separate dense bnapply
// normalizes once per element (zeros at inactive -> convs need no mask loads).
// XCD-swizzled tiles for L2 locality. No voxel lists anywhere.
// ---------------------------------------------------------------------------

typedef short bf16x8 __attribute__((ext_vector_type(8)));
typedef float f32x4 __attribute__((ext_vector_type(4)));
typedef unsigned short ushort_t;

constexpr int D1 = 48, DIM2 = 24, DIM3 = 12;
constexpr int N1 = D1 * D1 * D1;        // 110592
constexpr int N2 = DIM2 * DIM2 * DIM2;  // 13824
constexpr int N3 = DIM3 * DIM3 * DIM3;  // 1728

// ---- workspace layout (float offsets) ----
// raw (un-normalized) bf16 buffers:
constexpr size_t OFF_X0   = 0;          // N1*32 bf16 (1,769,472 fl)
constexpr size_t OFF_B1A  = 1769472;    // b1a raw; later h1 raw
constexpr size_t OFF_CAT1 = 3538944;    // x1 | u1 raw (N1*64)
constexpr size_t OFF_T1   = 7077888;    // t1 raw
constexpr size_t OFF_D1   = 8847360;    // d1 raw (N2*64)
constexpr size_t OFF_R3   = 9289728;    // b2a; h2 raw
constexpr size_t OFF_CAT2 = 9732096;    // x2 | u2 raw (N2*128)
constexpr size_t OFF_T2   = 10616832;   // t2 raw
constexpr size_t OFF_D2   = 11059200;   // N3*96
constexpr size_t OFF_R4   = 11142144;
constexpr size_t OFF_X3   = 11225088;
// normalized bf16 buffers (exact zeros at inactive):
constexpr size_t OFF_NB32   = 11308032; // N1*32
constexpr size_t OFF_NB64   = 13077504; // N1*64
constexpr size_t OFF_NB2_64 = 16616448; // N2*64
constexpr size_t OFF_NB2_128= 17058816; // N2*128
constexpr size_t OFF_NB3    = 17943552; // N3*96
constexpr size_t OFF_WT     = 18026496; // bf16 weights (1,347,584 us)
constexpr size_t OFF_STATS  = 18700288; // 16 slots * 8 reps * 256 doubles
constexpr size_t STATS_FLOATS = 16 * 4096;
constexpr size_t OFF_CNT    = OFF_STATS + STATS_FLOATS;  // n1,n2,n3
constexpr size_t OFF_M1     = OFF_CNT + 16;
constexpr size_t OFF_M2     = OFF_M1 + N1 / 4;
constexpr size_t OFF_M3     = OFF_M2 + N2 / 4;

// bf16 weight starts (ushort units), layout [k][co][cipad]
// jobs: 0 w_in, 1 b1a, 2 b1b, 3 d1, 4 b2a, 5 b2b, 6 d2, 7 b3a, 8 b3b,
//       9 t2a(128ci), 10 t2b, 11 t1a, 12 t1b, 13 u2, 14 u1
constexpr int WTS[16] = {0, 27648, 55296, 82944, 99328, 209920, 320512,
                         369664, 618496, 867328, 1088512, 1199104, 1254400,
                         1282048, 1331200, 1347584};
constexpr int WTOT = 1347584;

__device__ inline ushort_t f2bf(float f) {
  union { float f; unsigned u; } x; x.f = f;
  unsigned u = x.u + 0x7FFF + ((x.u >> 16) & 1);
  return (ushort_t)(u >> 16);
}
__device__ inline float bf2f(unsigned u16) {
  union { unsigned u; float f; } x; x.u = u16 << 16;
  return x.f;
}

// ---------------------------------------------------------------------------
// prep: mask1 + count n1 + weight conversion (fused). pools: mask + count.
// ---------------------------------------------------------------------------
struct WJobs {
  const float* src[15];
  int start[16];
  short cirt[15], cip[15], cot[15];
};

__global__ __launch_bounds__(256) void k_prep(WJobs jb, const float* __restrict__ x,
                                              unsigned char* __restrict__ m,
                                              int* __restrict__ cnt,
                                              ushort_t* __restrict__ wt) {
  int gid = blockIdx.x * 256 + threadIdx.x;
  int gs = gridDim.x * 256;
  for (int v = gid; v < N1; v += gs) {
    const float* p = x + (size_t)v * 6;
    bool a = (p[0] != 0.f) || (p[1] != 0.f) || (p[2] != 0.f) ||
             (p[3] != 0.f) || (p[4] != 0.f) || (p[5] != 0.f);
    m[v] = a ? 1 : 0;
    if (a) atomicAdd(cnt, 1);
  }
  for (int e = gid; e < WTOT; e += gs) {
    int j = 0;
#pragma unroll
    for (int jj = 0; jj < 15; jj++)
      if (e >= jb.start[jj + 1]) j = jj + 1;
    int le = e - jb.start[j];
    int CIP = jb.cip[j], CO = jb.cot[j], CIRT = jb.cirt[j];
    int ci = le % CIP;
    int co = (le / CIP) % CO;
    int k = le / (CIP * CO);
    float v = (ci < CIRT) ? jb.src[j][((size_t)k * CIRT + ci) * CO + co] : 0.f;
    wt[e] = f2bf(v);
  }
}

__global__ __launch_bounds__(256) void k_pool(const unsigned char* __restrict__ mf,
                                              unsigned char* __restrict__ mc,
                                              int* __restrict__ cnt, int DC) {
  int v = blockIdx.x * 256 + threadIdx.x;
  int n = DC * DC * DC;
  if (v >= n) return;
  int w = v % DC, h = (v / DC) % DC, d = v / (DC * DC);
  int DF = 2 * DC;
  bool a = false;
  for (int i = 0; i < 2; i++)
    for (int j = 0; j < 2; j++)
      for (int k = 0; k < 2; k++)
        a |= (mf[(size_t)(((2 * d + i) * DF + (2 * h + j)) * DF + (2 * w + k))] != 0);
  mc[v] = a ? 1 : 0;
  if (a) atomicAdd(cnt, 1);
}

// ---------------------------------------------------------------------------
// Dense MFMA conv. Grid: x = tile (32 voxels, XCD-swizzled), y = co-block.
// 8 waves = 2 voxel-groups x 4 tap-splits; per-wave weight slice in VGPRs;
// A = coalesced flat-shifted bf16x8 loads from normalized input (zeros at
// inactive); OOB taps zeroed via cndmask. Epilogue: 4-way LDS reduce, bf16
// store (+bf16 residual or fused 1x1-shortcut), mask-gated BN stats.
// ---------------------------------------------------------------------------
template <int CIPAD, int CB, int KK, int DD, bool UP, bool RAW6, int SCCI>
__global__ __launch_bounds__(512) void k_dconv(
    const void* __restrict__ in_, int istr,
    const ushort_t* __restrict__ wt, int cot,
    ushort_t* __restrict__ outp, int ostr, int ooff,
    const ushort_t* __restrict__ res, int rstr,
    const ushort_t* __restrict__ scIn, int scstr, const float* __restrict__ scW,
    const unsigned char* __restrict__ mskOut,
    double* __restrict__ stOut) {
  constexpr int KCH = CIPAD / 32;
  constexpr int NCO = CB / 16;
  constexpr int TPS = (KK + 3) / 4;
  constexpr int NVOX = DD * DD * DD;
  constexpr int NT = NVOX / 32;  // exact for 48/24/12 grids
  constexpr int GDI = UP ? (DD / 2) : ((KK == 8) ? 2 * DD : DD);
  constexpr int ETOT = 2 * NCO * 256;
  constexpr int NE = ETOT / 512;
  __shared__ float red[4][2][NCO * 4][64];
  __shared__ float sred[2 * CB];

  const int t = threadIdx.x, wv = t >> 6, ln = t & 63;
  const int vg = wv & 1, ks = wv >> 1;
  const int fr = ln & 15, kg = ln >> 4;
  const int coblk = blockIdx.y * CB;
  const int k0 = ks * TPS;

  // bijective XCD swizzle over tiles
  constexpr int QQ = NT / 8, RR = NT % 8;
  int bid = blockIdx.x;
  int xcd = bid & 7, lid = bid >> 3;
  int tile = (xcd < RR ? xcd * (QQ + 1) : RR * (QQ + 1) + (xcd - RR) * QQ) + lid;

  if (t < 2 * CB) sred[t] = 0.f;

  // per-wave weight slice in registers
  bf16x8 wr[TPS][KCH][NCO];
#pragma unroll
  for (int j = 0; j < TPS; j++) {
    int kk = k0 + j;
    int kc = (kk < KK) ? kk : KK - 1;
#pragma unroll
    for (int c = 0; c < KCH; c++)
#pragma unroll
      for (int f = 0; f < NCO; f++)
        wr[j][c][f] = *(const bf16x8*)(wt +
            ((size_t)kc * cot + coblk + f * 16 + fr) * CIPAD + c * 32 + kg * 8);
  }

  const int base = tile * 32;
  const int v = base + vg * 16 + fr;
  const int vw = v % DD, vh = (v / DD) % DD, vd = v / (DD * DD);
  int pidx = 0, corner = -1;
  if (UP) {
    constexpr int DC = DD / 2;
    pidx = (((vd >> 1) * DC) + (vh >> 1)) * DC + (vw >> 1);
    corner = ((vd & 1) << 2) | ((vh & 1) << 1) | (vw & 1);
  }

  const ushort_t* inb = (const ushort_t*)in_;
  const float* inf = (const float*)in_;

  bf16x8 aR[2][KCH];
  float aF6[2][6];
  bool okv[2];

  auto LOADT = [&](int st, int j) {
    int k = k0 + j;
    int kc = (k < KK) ? k : KK - 1;
    bool ok;
    int nix;
    if (UP) {
      ok = (k < KK) && (corner == kc);
      nix = pidx;
    } else if (KK == 27) {
      int kd = kc / 9 - 1, kh = (kc / 3) % 3 - 1, kw = kc % 3 - 1;
      ok = (k < KK) && ((unsigned)(vw + kw) < (unsigned)DD) &&
           ((unsigned)(vh + kh) < (unsigned)DD) && ((unsigned)(vd + kd) < (unsigned)DD);
      nix = v + (kd * DD + kh) * DD + kw;
    } else {
      ok = (k < KK);
      nix = ((2 * vd + ((kc >> 2) & 1)) * GDI + (2 * vh + ((kc >> 1) & 1))) * GDI +
            (2 * vw + (kc & 1));
    }
    nix = ok ? nix : 0;
    okv[st] = ok;
    if (RAW6) {
      const float* xp = inf + (size_t)nix * 6;
      if (kg == 0) {
#pragma unroll
        for (int q = 0; q < 6; q++) aF6[st][q] = xp[q];
      }
    } else {
#pragma unroll
      for (int c = 0; c < KCH; c++)
        aR[st][c] = *(const bf16x8*)(inb + (size_t)nix * istr + c * 32 + kg * 8);
    }
  };

  f32x4 acc[NCO];
#pragma unroll
  for (int f = 0; f < NCO; f++) acc[f] = (f32x4){0.f, 0.f, 0.f, 0.f};

  LOADT(0, 0);
#pragma unroll
  for (int j = 0; j < TPS; j++) {
    if (j + 1 < TPS) LOADT((j + 1) & 1, j + 1);
    const int st = j & 1;
    if (k0 + j < KK) {
#pragma unroll
      for (int c = 0; c < KCH; c++) {
        bf16x8 af;
        if (RAW6) {
          if (kg == 0 && okv[st]) {
            bf16x8 tmp;
#pragma unroll
            for (int q = 0; q < 6; q++) tmp[q] = (short)f2bf(aF6[st][q]);
            tmp[6] = 0; tmp[7] = 0;
            af = tmp;
          } else {
            af = (bf16x8){0, 0, 0, 0, 0, 0, 0, 0};
          }
        } else {
          af = okv[st] ? aR[st][c] : (bf16x8){0, 0, 0, 0, 0, 0, 0, 0};
        }
#pragma unroll
        for (int f = 0; f < NCO; f++)
          acc[f] = __builtin_amdgcn_mfma_f32_16x16x32_bf16(af, wr[j][c][f], acc[f], 0, 0, 0);
      }
    }
  }

#pragma unroll
  for (int f = 0; f < NCO; f++)
#pragma unroll
    for (int r = 0; r < 4; r++)
      red[ks][vg][f * 4 + r][ln] = acc[f][r];
  __syncthreads();

#pragma unroll
  for (int e0 = 0; e0 < NE; e0++) {
    int e = t + e0 * 512;
    int ln2 = e & 63, r = (e >> 6) & 3;
    int f = (e >> 8) % NCO;
    int vg2 = e / (256 * NCO);
    float val = red[0][vg2][f * 4 + r][ln2] + red[1][vg2][f * 4 + r][ln2] +
                red[2][vg2][f * 4 + r][ln2] + red[3][vg2][f * 4 + r][ln2];
    int slot = vg2 * 16 + (ln2 >> 4) * 4 + r;
    int v2 = base + slot;
    int gco = coblk + f * 16 + (ln2 & 15);
    if (SCCI > 0) {
      const ushort_t* xr = scIn + (size_t)v2 * scstr;
      const float* wq = scW + (size_t)gco * SCCI;
      float a = 0.f;
#pragma unroll 4
      for (int c = 0; c < SCCI; c += 8) {
        uint4 u = *(const uint4*)&xr[c];
        a += bf2f(u.x & 0xffff) * wq[c + 0] + bf2f(u.x >> 16) * wq[c + 1] +
             bf2f(u.y & 0xffff) * wq[c + 2] + bf2f(u.y >> 16) * wq[c + 3] +
             bf2f(u.z & 0xffff) * wq[c + 4] + bf2f(u.z >> 16) * wq[c + 5] +
             bf2f(u.w & 0xffff) * wq[c + 6] + bf2f(u.w >> 16) * wq[c + 7];
      }
      val += a;
    } else if (res) {
      val += bf2f((unsigned)res[(size_t)v2 * rstr + gco]);
    }
    outp[(size_t)v2 * ostr + ooff + gco] = f2bf(val);
    float mf = mskOut[v2] ? 1.f : 0.f;
    atomicAdd(&sred[f * 16 + (ln2 & 15)], val * mf);
    atomicAdd(&sred[CB + f * 16 + (ln2 & 15)], val * val * mf);
  }
  __syncthreads();
  if (t < CB) {
    double* sr = stOut + (size_t)((int)blockIdx.x & 7) * 256;
    atomicAdd(&sr[coblk + t], (double)sred[t]);
    atomicAdd(&sr[128 + coblk + t], (double)sred[CB + t]);
  }
}

// ---------------------------------------------------------------------------
// dense BN apply: raw bf16 -> normalized bf16 (exact zeros at inactive).
// ---------------------------------------------------------------------------
template <int C>
__global__ __launch_bounds__(256) void k_bnapply(
    const ushort_t* __restrict__ in, int istr, int icoff,
    const unsigned char* __restrict__ m, const int* __restrict__ cnt,
    const double* __restrict__ sA, const double* __restrict__ sB, int csplit,
    ushort_t* __restrict__ outp, int N) {
  __shared__ float s_iv[C], s_mv[C];
  int t = threadIdx.x;
  int n = cnt[0];
  if (t < C) {
    const double* s = (t < csplit) ? (sA + t) : (sB + (t - csplit));
    double sm = 0.0, sq = 0.0;
#pragma unroll
    for (int r = 0; r < 8; r++) { sm += s[r * 256]; sq += s[r * 256 + 128]; }
    double mu = sm / n, var = sq / n - mu * mu;
    float iv = rsqrtf((float)fmax(var, 0.0) + 1e-4f);
    s_iv[t] = iv;
    s_mv[t] = (float)mu * iv;
  }
  __syncthreads();
  int gid = blockIdx.x * 256 + t;
  if (gid >= N * (C / 8)) return;
  int v = gid / (C / 8), c8 = (gid % (C / 8)) * 8;
  uint4 rw = *(const uint4*)&in[(size_t)v * istr + icoff + c8];
  float mf = m[v] ? 1.f : 0.f;
  unsigned uu[4] = {rw.x, rw.y, rw.z, rw.w};
  uint4 ow;
  unsigned* op = &ow.x;
#pragma unroll
  for (int p = 0; p < 4; p++) {
    int c = c8 + 2 * p;
    float lo = fmaxf(fmaf(bf2f(uu[p] & 0xffff), s_iv[c], -s_mv[c]), 0.f) * mf;
    float hi = fmaxf(fmaf(bf2f(uu[p] >> 16), s_iv[c + 1], -s_mv[c + 1]), 0.f) * mf;
    op[p] = (unsigned)f2bf(lo) | ((unsigned)f2bf(hi) << 16);
  }
  *(uint4*)&outp[(size_t)v * C + c8] = ow;
}

// final BN apply -> dense f32 d_out (exact zeros at inactive)
__global__ __launch_bounds__(256) void k_bnout(const ushort_t* __restrict__ x,
                                               const unsigned char* __restrict__ m,
                                               const double* __restrict__ s,
                                               const int* __restrict__ cnt,
                                               float* __restrict__ out) {
  __shared__ float s_iv[32], s_mv[32];
  int t = threadIdx.x;
  int n = cnt[0];
  if (t < 32) {
    const double* sp = s + t;
    double sm = 0.0, sq = 0.0;
#pragma unroll
    for (int r = 0; r < 8; r++) { sm += sp[r * 256]; sq += sp[r * 256 + 128]; }
    double mu = sm / n, var = sq / n - mu * mu;
    float iv = rsqrtf((float)fmax(var, 0.0) + 1e-4f);
    s_iv[t] = iv;
    s_mv[t] = (float)mu * iv;
  }
  __syncthreads();
  int gid = blockIdx.x * 256 + t;
  if (gid >= N1 * 8) return;
  int v = gid >> 3, c = (gid & 7) * 4;
  float4 o = make_float4(0.f, 0.f, 0.f, 0.f);
  if (m[v]) {
    uint2 u = *(const uint2*)&x[(size_t)v * 32 + c];
    o.x = fmaxf(fmaf(bf2f(u.x & 0xffff), s_iv[c + 0], -s_mv[c + 0]), 0.f);
    o.y = fmaxf(fmaf(bf2f(u.x >> 16), s_iv[c + 1], -s_mv[c + 1]), 0.f);
    o.z = fmaxf(fmaf(bf2f(u.y & 0xffff), s_iv[c + 2], -s_mv[c + 2]), 0.f);
    o.w = fmaxf(fmaf(bf2f(u.y >> 16), s_iv[c + 3], -s_mv[c + 3]), 0.f);
  }
  *(float4*)&out[(size_t)v * 32 + c] = o;
}

// ---------------------------------------------------------------------------
// host launch
// ---------------------------------------------------------------------------
extern "C" void kernel_launch(void* const* d_in, const int* in_sizes, int n_in,
                              void* d_out, int out_size, void* d_ws, size_t ws_size,
                              hipStream_t stream) {
  float* W = (float*)d_ws;
  const float* x = (const float*)d_in[0];

  ushort_t* X0b  = (ushort_t*)(W + OFF_X0);
  ushort_t* B1Ab = (ushort_t*)(W + OFF_B1A);
  ushort_t* CAT1b= (ushort_t*)(W + OFF_CAT1);
  ushort_t* T1b  = (ushort_t*)(W + OFF_T1);
  ushort_t* D1b  = (ushort_t*)(W + OFF_D1);
  ushort_t* R3b  = (ushort_t*)(W + OFF_R3);
  ushort_t* CAT2b= (ushort_t*)(W + OFF_CAT2);
  ushort_t* T2b  = (ushort_t*)(W + OFF_T2);
  ushort_t* D2b  = (ushort_t*)(W + OFF_D2);
  ushort_t* R4b  = (ushort_t*)(W + OFF_R4);
  ushort_t* X3b  = (ushort_t*)(W + OFF_X3);
  ushort_t* NB32 = (ushort_t*)(W + OFF_NB32);
  ushort_t* NB64 = (ushort_t*)(W + OFF_NB64);
  ushort_t* NB2_64 = (ushort_t*)(W + OFF_NB2_64);
  ushort_t* NB2_128= (ushort_t*)(W + OFF_NB2_128);
  ushort_t* NB3  = (ushort_t*)(W + OFF_NB3);
  ushort_t* WT   = (ushort_t*)(W + OFF_WT);
  double* S0 = (double*)(W + OFF_STATS);
  int* CNT = (int*)(W + OFF_CNT);
  unsigned char* M1 = (unsigned char*)(W + OFF_M1);
  unsigned char* M2 = (unsigned char*)(W + OFF_M2);
  unsigned char* M3 = (unsigned char*)(W + OFF_M3);
  const float* wsc2 = (const float*)d_in[12];
  const float* wsc1 = (const float*)d_in[16];

  auto S = [&](int i) { return S0 + (size_t)i * 2048; };
  // slots: 0 x0, 1 b1a, 2 x1, 3 d1, 4 b2a, 5 x2, 6 d2, 7 b3a, 8 x3,
  //        9 u2, 10 h2, 11 t2, 12 u1, 13 h1, 14 t1

  hipMemsetAsync(W + OFF_STATS, 0, (STATS_FLOATS + 16) * 4, stream);

  WJobs jb;
  const int srcIdx[15] = {2, 3, 4, 5, 6, 7, 8, 9, 10, 13, 14, 17, 18, 11, 15};
  const short cirt[15] = {6, 32, 32, 32, 64, 64, 64, 96, 96, 128, 64, 64, 32, 96, 64};
  const short cip[15]  = {32, 32, 32, 32, 64, 64, 64, 96, 96, 128, 64, 64, 32, 96, 64};
  const short cot[15]  = {32, 32, 32, 64, 64, 64, 96, 96, 96, 64, 64, 32, 32, 64, 32};
  for (int j = 0; j < 15; j++) {
    jb.src[j] = (const float*)d_in[srcIdx[j]];
    jb.cirt[j] = cirt[j]; jb.cip[j] = cip[j]; jb.cot[j] = cot[j];
    jb.start[j] = WTS[j];
  }
  jb.start[15] = WTS[15];

  k_prep<<<864, 256, 0, stream>>>(jb, x, M1, CNT + 0, WT);
  k_pool<<<N2 / 256, 256, 0, stream>>>(M1, M2, CNT + 1, DIM2);
  k_pool<<<(N3 + 255) / 256, 256, 0, stream>>>(M2, M3, CNT + 2, DIM3);

  const int NT1 = N1 / 32, NT2 = N2 / 32, NT3 = N3 / 32;  // 3456, 432, 54

  // ---- level 1 down ----
  k_dconv<32, 32, 27, D1, false, true, 0><<<dim3(NT1, 1), 512, 0, stream>>>(
      x, 6, WT + WTS[0], 32, X0b, 32, 0, nullptr, 0, nullptr, 0, nullptr, M1, S(0));   // x0
  k_bnapply<32><<<1728, 256, 0, stream>>>(X0b, 32, 0, M1, CNT + 0, S(0), S(0), 32, NB32, N1);
  k_dconv<32, 32, 27, D1, false, false, 0><<<dim3(NT1, 1), 512, 0, stream>>>(
      NB32, 32, WT + WTS[1], 32, B1Ab, 32, 0, nullptr, 0, nullptr, 0, nullptr, M1, S(1)); // b1a
  k_bnapply<32><<<1728, 256, 0, stream>>>(B1Ab, 32, 0, M1, CNT + 0, S(1), S(1), 32, NB32, N1);
  k_dconv<32, 32, 27, D1, false, false, 0><<<dim3(NT1, 1), 512, 0, stream>>>(
      NB32, 32, WT + WTS[2], 32, CAT1b, 64, 0, X0b, 32, nullptr, 0, nullptr, M1, S(2));   // x1
  k_bnapply<32><<<1728, 256, 0, stream>>>(CAT1b, 64, 0, M1, CNT + 0, S(2), S(2), 32, NB32, N1);
  k_dconv<32, 32, 8, DIM2, false, false, 0><<<dim3(NT2, 2), 512, 0, stream>>>(
      NB32, 32, WT + WTS[3], 64, D1b, 64, 0, nullptr, 0, nullptr, 0, nullptr, M2, S(3));  // d1

  // ---- level 2 ----
  k_bnapply<64><<<432, 256, 0, stream>>>(D1b, 64, 0, M2, CNT + 1, S(3), S(3), 64, NB2_64, N2);
  k_dconv<64, 16, 27, DIM2, false, false, 0><<<dim3(NT2, 4), 512, 0, stream>>>(
      NB2_64, 64, WT + WTS[4], 64, R3b, 64, 0, nullptr, 0, nullptr, 0, nullptr, M2, S(4)); // b2a
  k_bnapply<64><<<432, 256, 0, stream>>>(R3b, 64, 0, M2, CNT + 1, S(4), S(4), 64, NB2_64, N2);
  k_dconv<64, 16, 27, DIM2, false, false, 0><<<dim3(NT2, 4), 512, 0, stream>>>(
      NB2_64, 64, WT + WTS[5], 64, CAT2b, 128, 0, D1b, 64, nullptr, 0, nullptr, M2, S(5)); // x2
  k_bnapply<64><<<432, 256, 0, stream>>>(CAT2b, 128, 0, M2, CNT + 1, S(5), S(5), 64, NB2_64, N2);
  k_dconv<64, 32, 8, DIM3, false, false, 0><<<dim3(NT3, 3), 512, 0, stream>>>(
      NB2_64, 64, WT + WTS[6], 96, D2b, 96, 0, nullptr, 0, nullptr, 0, nullptr, M3, S(6)); // d2

  // ---- level 3 ----
  k_bnapply<96><<<81, 256, 0, stream>>>(D2b, 96, 0, M3, CNT + 2, S(6), S(6), 96, NB3, N3);
  k_dconv<96, 16, 27, DIM3, false, false, 0><<<dim3(NT3, 6), 512, 0, stream>>>(
      NB3, 96, WT + WTS[7], 96, R4b, 96, 0, nullptr, 0, nullptr, 0, nullptr, M3, S(7));    // b3a
  k_bnapply<96><<<81, 256, 0, stream>>>(R4b, 96, 0, M3, CNT + 2, S(7), S(7), 96, NB3, N3);
  k_dconv<96, 16, 27, DIM3, false, false, 0><<<dim3(NT3, 6), 512, 0, stream>>>(
      NB3, 96, WT + WTS[8], 96, X3b, 96, 0, D2b, 96, nullptr, 0, nullptr, M3, S(8));       // x3
  k_bnapply<96><<<81, 256, 0, stream>>>(X3b, 96, 0, M3, CNT + 2, S(8), S(8), 96, NB3, N3);
  k_dconv<96, 32, 8, DIM2, true, false, 0><<<dim3(NT2, 2), 512, 0, stream>>>(
      NB3, 96, WT + WTS[13], 64, CAT2b, 128, 64, nullptr, 0, nullptr, 0, nullptr, M2, S(9)); // u2

  // ---- tail level 2 ----
  k_bnapply<128><<<864, 256, 0, stream>>>(CAT2b, 128, 0, M2, CNT + 1, S(5), S(9), 64, NB2_128, N2);
  k_dconv<128, 16, 27, DIM2, false, false, 0><<<dim3(NT2, 4), 512, 0, stream>>>(
      NB2_128, 128, WT + WTS[9], 64, R3b, 64, 0, nullptr, 0, nullptr, 0, nullptr, M2, S(10)); // h2
  k_bnapply<64><<<432, 256, 0, stream>>>(R3b, 64, 0, M2, CNT + 1, S(10), S(10), 64, NB2_64, N2);
  k_dconv<64, 16, 27, DIM2, false, false, 128><<<dim3(NT2, 4), 512, 0, stream>>>(
      NB2_64, 64, WT + WTS[10], 64, T2b, 64, 0, nullptr, 0, CAT2b, 128, wsc2, M2, S(11));  // t2 (+sc)
  k_bnapply<64><<<432, 256, 0, stream>>>(T2b, 64, 0, M2, CNT + 1, S(11), S(11), 64, NB2_64, N2);
  k_dconv<64, 32, 8, D1, true, false, 0><<<dim3(NT1, 1), 512, 0, stream>>>(
      NB2_64, 64, WT + WTS[14], 32, CAT1b, 64, 32, nullptr, 0, nullptr, 0, nullptr, M1, S(12)); // u1

  // ---- tail level 1 ----
  k_bnapply<64><<<3456, 256, 0, stream>>>(CAT1b, 64, 0, M1, CNT + 0, S(2), S(12), 32, NB64, N1);
  k_dconv<64, 16, 27, D1, false, false, 0><<<dim3(NT1, 2), 512, 0, stream>>>(
      NB64, 64, WT + WTS[11], 32, B1Ab, 32, 0, nullptr, 0, nullptr, 0, nullptr, M1, S(13)); // h1
  k_bnapply<32><<<1728, 256, 0, stream>>>(B1Ab, 32, 0, M1, CNT + 0, S(13), S(13), 32, NB32, N1);
  k_dconv<32, 32, 27, D1, false, false, 64><<<dim3(NT1, 1), 512, 0, stream>>>(
      NB32, 32, WT + WTS[12], 32, T1b, 32, 0, nullptr, 0, CAT1b, 64, wsc1, M1, S(14));     // t1 (+sc)

  k_bnout<<<3456, 256, 0, stream>>>(T1b, M1, S(14), CNT + 0, (float*)d_out);
}

// Round 12
// 413.625 us; speedup vs baseline: 2.6313x; 2.6313x over previous
//
#include <hip/hip_runtime.h>

// ---------------------------------------------------------------------------
// SparseConvUNet forward, round 12: R8 sparse structure + PINNED register
// weights (asm "+v" defeats rematerialization), VG=1/KS=8 (4-tap serial
// chain), CB=32 co-blocks. Sentinel zero rows; gather BN-apply to bf16;
// fused BN stats with x8-replicated f64 atomics.
// ---------------------------------------------------------------------------

typedef short bf16x8 __attribute__((ext_vector_type(8)));
typedef float f32x4 __attribute__((ext_vector_type(4)));
typedef unsigned short ushort_t;

constexpr int D1 = 48, DIM2 = 24, DIM3 = 12;
constexpr int N1 = D1 * D1 * D1;        // 110592
constexpr int N2 = DIM2 * DIM2 * DIM2;  // 13824
constexpr int N3 = DIM3 * DIM3 * DIM3;  // 1728

// ---- workspace layout (float offsets) ----
constexpr size_t OFF_A      = 0;               // x0; idb1; t1 (in-place res)
constexpr size_t OFF_R1     = 3538944;         // b1a_raw; h1_raw
constexpr size_t OFF_CAT1   = 7077888;         // XP overlay; then x1|u1 (N1*64)
constexpr size_t OFF_D1R    = 14155776;        // d1_raw; idb2 (N2*64)
constexpr size_t OFF_R3     = 15040512;        // b2a_raw; h2_raw; t2_raw
constexpr size_t OFF_CAT2   = 15925248;        // x2|u2 (N2*128)
constexpr size_t OFF_D2R    = 17694720;        // N3*96
constexpr size_t OFF_R4     = 17860608;        // N3*96
constexpr size_t OFF_X3R    = 18026496;        // N3*96
// bf16 dense-zeroed buffers, each with >=1 zero sentinel row
constexpr size_t OFF_BN1_32 = 18192384;        // (N1*32+128) us
constexpr size_t OFF_BN1_64 = 19961920;        // (N1*64+128) us
constexpr size_t OFF_BN2_A  = 23500928;        // (N2*64+128) us
constexpr size_t OFF_BN2_B  = 23943360;        // (N2*64+128) us
constexpr size_t OFF_BN3_96 = 24385792;        // (N3*96+128) us
constexpr size_t OFF_BFEND  = 24468800;        // zeroed region end
constexpr size_t OFF_WT     = 24468800;        // bf16 weights (1,347,584 us)
constexpr size_t OFF_STATS  = 25142592;        // 16 slots * 8 reps * 256 doubles
constexpr size_t STATS_FLOATS = 16 * 4096;
constexpr size_t OFF_CNT    = OFF_STATS + STATS_FLOATS;
constexpr size_t OFF_L1     = OFF_CNT + 16;
constexpr size_t OFF_L2     = OFF_L1 + N1;
constexpr size_t OFF_L3     = OFF_L2 + N2;
constexpr size_t OFF_M1     = OFF_L3 + N3;
constexpr size_t OFF_M2     = OFF_M1 + N1 / 4;
constexpr size_t OFF_M3     = OFF_M2 + N2 / 4;

// bf16 weight starts (ushort units), layout [k][co][cipad], exact taps.
// jobs: 0 w_in, 1 b1a, 2 b1b, 3 d1, 4 b2a, 5 b2b, 6 d2, 7 b3a, 8 b3b,
//       9 t2aA(ci 0:64), 10 t2aB(ci 64:128), 11 t2b, 12 t1a, 13 t1b, 14 u2, 15 u1
constexpr int WTS[17] = {0, 27648, 55296, 82944, 99328, 209920, 320512,
                         369664, 618496, 867328, 977920, 1088512, 1199104,
                         1254400, 1282048, 1331200, 1347584};

__device__ inline ushort_t f2bf(float f) {
  union { float f; unsigned u; } x; x.f = f;
  unsigned u = x.u + 0x7FFF + ((x.u >> 16) & 1);
  return (ushort_t)(u >> 16);
}

// pin a value into a VGPR tuple: volatile in-out asm cannot be rematerialized
#define KEEP8(x) asm volatile("" : "+v"(x))

// ---------------------------------------------------------------------------
// mask / list kernels
// ---------------------------------------------------------------------------
__global__ __launch_bounds__(256) void k_mask1(const float* __restrict__ x,
                                               unsigned char* __restrict__ m,
                                               int* __restrict__ list, int* __restrict__ cnt) {
  int v = blockIdx.x * 256 + threadIdx.x;
  if (v >= N1) return;
  const float* p = x + (size_t)v * 6;
  bool a = (p[0] != 0.f) || (p[1] != 0.f) || (p[2] != 0.f) ||
           (p[3] != 0.f) || (p[4] != 0.f) || (p[5] != 0.f);
  m[v] = a ? 1 : 0;
  if (a) { int pos = atomicAdd(cnt, 1); list[pos] = v; }
}

__global__ __launch_bounds__(256) void k_pool(const unsigned char* __restrict__ mf,
                                              unsigned char* __restrict__ mc,
                                              int* __restrict__ list, int* __restrict__ cnt, int DC) {
  int v = blockIdx.x * 256 + threadIdx.x;
  int n = DC * DC * DC;
  if (v >= n) return;
  int w = v % DC, h = (v / DC) % DC, d = v / (DC * DC);
  int DF = 2 * DC;
  bool a = false;
  for (int i = 0; i < 2; i++)
    for (int j = 0; j < 2; j++)
      for (int k = 0; k < 2; k++)
        a |= (mf[(size_t)(((2 * d + i) * DF + (2 * h + j)) * DF + (2 * w + k))] != 0);
  mc[v] = a ? 1 : 0;
  if (a) { int pos = atomicAdd(cnt, 1); list[pos] = v; }
}

// ---------------------------------------------------------------------------
// weight prep: f32 [k][ci_total][co] -> bf16 [k][co][cipad] (ci slice via cio)
// ---------------------------------------------------------------------------
struct WJobs {
  const float* src[16];
  int start[17];
  short cirtot[16], cio[16], cipad[16], cout[16];
};

__global__ __launch_bounds__(256) void k_wprep(WJobs jb, ushort_t* __restrict__ wt, int total) {
  int gid = blockIdx.x * 256 + threadIdx.x;
  if (gid >= total) return;
  int j = 0;
#pragma unroll
  for (int jj = 0; jj < 16; jj++)
    if (gid >= jb.start[jj + 1]) j = jj + 1;
  int e = gid - jb.start[j];
  int CIP = jb.cipad[j], CO = jb.cout[j];
  int CIRT = jb.cirtot[j], CIO = jb.cio[j];
  int ci = e % CIP;
  int co = (e / CIP) % CO;
  int k = e / (CIP * CO);
  float v = (ci + CIO < CIRT) ? jb.src[j][((size_t)k * CIRT + CIO + ci) * CO + co] : 0.f;
  wt[gid] = f2bf(v);
}

// x (N1 x 6 f32) -> dense bf16 (N1+4) x 32 (zero-padded ci, zero sentinel rows)
__global__ __launch_bounds__(256) void k_xprep(const float* __restrict__ x, ushort_t* __restrict__ xp) {
  int gid = blockIdx.x * 256 + threadIdx.x;
  if (gid >= (N1 + 4) * 8) return;
  int v = gid >> 3, c = (gid & 7) * 4;
  uint2 o = make_uint2(0u, 0u);
  if (v < N1) {
    ushort_t u[4];
#pragma unroll
    for (int j = 0; j < 4; j++) {
      int ci = c + j;
      float f = (ci < 6) ? x[(size_t)v * 6 + ci] : 0.f;
      u[j] = f2bf(f);
    }
    o.x = (unsigned)u[0] | ((unsigned)u[1] << 16);
    o.y = (unsigned)u[2] | ((unsigned)u[3] << 16);
  }
  *(uint2*)&xp[(size_t)v * 32 + c] = o;
}

// ---------------------------------------------------------------------------
// Pinned-register-weight MFMA conv. Grid: x = tile stride (16 voxels),
// y = co-block (CB). Block = 8 waves, each owning tap set {ks, ks+8, ks+16,
// ks+24} (KS=8 split). Weight slice loaded ONCE into VGPRs and pinned with
// volatile asm (defeats rematerialization). Tile loop: A gathered direct from
// bf16 input (sentinel zero row for OOB/inactive/invalid-tap), 2-stage
// prefetch, MFMAs read B from registers. 8-way LDS reduce. Register BN stats.
// ---------------------------------------------------------------------------
template <int CIPAD, int CB, int KK, int DD, bool UP>
__global__ __launch_bounds__(512, 2) void k_conv12(
    const ushort_t* __restrict__ in, const ushort_t* __restrict__ wt, int cot,
    float* __restrict__ out, int ostride, int ooff,
    const float* __restrict__ res, int rstride,
    double* __restrict__ st,
    const int* __restrict__ list, const int* __restrict__ cnt) {
  constexpr int KCH = CIPAD / 32;
  constexpr int NCO = CB / 16;
  constexpr int TPS = (KK + 7) / 8;       // 27->4, 8->1
  constexpr int ETOT = NCO * 256;
  __shared__ float red[8][NCO * 4][64];
  __shared__ float sred[2 * CB];
  __shared__ int vidx[16];

  const int n = cnt[0];
  const int t = threadIdx.x, ks = t >> 6, ln = t & 63;
  const int fr = ln & 15, kg = ln >> 4;
  const int coblk = blockIdx.y * CB;

  // ---- load this wave's weight slice into registers ONCE, then pin ----
  bf16x8 wr[TPS][KCH][NCO];
#pragma unroll
  for (int j = 0; j < TPS; j++) {
    int kk = ks + j * 8;
    int kc = (kk < KK) ? kk : KK - 1;
#pragma unroll
    for (int c = 0; c < KCH; c++)
#pragma unroll
      for (int f = 0; f < NCO; f++)
        wr[j][c][f] = *(const bf16x8*)(wt +
            ((size_t)kc * cot + coblk + f * 16 + fr) * CIPAD + c * 32 + kg * 8);
  }
#pragma unroll
  for (int j = 0; j < TPS; j++)
#pragma unroll
    for (int c = 0; c < KCH; c++)
#pragma unroll
      for (int f = 0; f < NCO; f++) KEEP8(wr[j][c][f]);

  if (t < 2 * CB) sred[t] = 0.f;

  float smr = 0.f, sqr = 0.f;
  constexpr int GDI = UP ? (DD / 2) : ((KK == 8) ? 2 * DD : DD);
  constexpr int SENT = GDI * GDI * GDI;  // zero sentinel row

  for (int tile = blockIdx.x; tile * 16 < n; tile += gridDim.x) {
    int base = tile * 16;
    if (t < 16) vidx[t] = (base + t < n) ? list[base + t] : -1;
    __syncthreads();

    int av = vidx[fr];
    int vv = av < 0 ? 0 : av;
    int ad = vv / (DD * DD), ah = (vv / DD) % DD, aw = vv % DD;
    int pidx = 0, corner = -1;
    if (UP) {
      constexpr int DC = DD / 2;
      pidx = (((ad >> 1) * DC) + (ah >> 1)) * DC + (aw >> 1);
      corner = ((ad & 1) << 2) | ((ah & 1) << 1) | (aw & 1);
    }

    auto nixOf = [&](int kq) -> int {
      int kc = (kq < KK) ? kq : KK - 1;
      bool tapv = (kq < KK) && (av >= 0);
      if (UP) {
        return (tapv && corner == kc) ? pidx : SENT;
      } else if (KK == 27) {
        int kd = kc / 9 - 1, kh = (kc / 3) % 3 - 1, kw = kc % 3 - 1;
        int nd = ad + kd, nh = ah + kh, nw = aw + kw;
        bool inb = tapv && (unsigned)nd < (unsigned)DD &&
                   (unsigned)nh < (unsigned)DD && (unsigned)nw < (unsigned)DD;
        return inb ? (nd * DD + nh) * DD + nw : SENT;
      } else {
        return tapv ? ((2 * ad + ((kc >> 2) & 1)) * GDI + (2 * ah + ((kc >> 1) & 1))) * GDI +
                          (2 * aw + (kc & 1))
                    : SENT;
      }
    };
    auto loadA = [&](bf16x8* dst, int j) {
      int nix = nixOf(ks + j * 8);
      const ushort_t* ap = in + (size_t)nix * CIPAD + kg * 8;
#pragma unroll
      for (int c = 0; c < KCH; c++) dst[c] = *(const bf16x8*)(ap + c * 32);
    };

    f32x4 acc[NCO];
#pragma unroll
    for (int f = 0; f < NCO; f++) acc[f] = (f32x4){0.f, 0.f, 0.f, 0.f};

    bf16x8 aA[KCH], aB[KCH];
    loadA(aA, 0);
#pragma unroll
    for (int j = 0; j < TPS; j++) {
      if (j + 1 < TPS) loadA((j & 1) ? aA : aB, j + 1);
      bf16x8* cur = (j & 1) ? aB : aA;
#pragma unroll
      for (int c = 0; c < KCH; c++)
#pragma unroll
        for (int f = 0; f < NCO; f++)
          acc[f] = __builtin_amdgcn_mfma_f32_16x16x32_bf16(cur[c], wr[j][c][f], acc[f], 0, 0, 0);
    }

#pragma unroll
    for (int f = 0; f < NCO; f++)
#pragma unroll
      for (int r = 0; r < 4; r++)
        red[ks][f * 4 + r][ln] = acc[f][r];
    __syncthreads();

    if (t < ETOT) {
      int ln2 = t & 63, r = (t >> 6) & 3;
      int f = (t >> 8);
      float sv = 0.f;
#pragma unroll
      for (int q = 0; q < 8; q++) sv += red[q][f * 4 + r][ln2];
      int slot = (ln2 >> 4) * 4 + r;
      int ii = base + slot;
      int v = (ii < n) ? list[ii] : -1;
      if (v >= 0) {
        int gco = coblk + f * 16 + (ln2 & 15);
        float val = sv;
        if (res) val += res[(size_t)v * rstride + gco];
        out[(size_t)v * ostride + ooff + gco] = val;
        smr += val;
        sqr += val * val;
      }
    }
    __syncthreads();
  }

  // ---- block stats -> LDS reduce -> replicated global f64 atomics ----
  if (t < ETOT) {
    int myco = (t >> 8) * 16 + (t & 15);
    atomicAdd(&sred[myco], smr);
    atomicAdd(&sred[CB + myco], sqr);
  }
  __syncthreads();
  if (t < CB) {
    double* sr = st + (size_t)((int)blockIdx.x & 7) * 256;
    atomicAdd(&sr[coblk + t], (double)sred[t]);
    atomicAdd(&sr[128 + coblk + t], (double)sred[CB + t]);
  }
}

// ---------------------------------------------------------------------------
// BN apply (gather) with replica-finalize prologue. Source col offset coff;
// channels c < csplit use slot sA else sB. Output dense-zeroed bf16.
// ---------------------------------------------------------------------------
template <int C>
__global__ __launch_bounds__(256) void k_bnapply2(
    const float* __restrict__ x, int xstr, int coff,
    const double* __restrict__ sA, const double* __restrict__ sB, int csplit,
    const int* __restrict__ list, const int* __restrict__ cnt,
    ushort_t* __restrict__ out) {
  __shared__ float mu_s[C], inv_s[C];
  int n = cnt[0];
  int t = threadIdx.x;
  if (t < C) {
    const double* s = (t < csplit) ? (sA + t) : (sB + (t - csplit));
    double sm = 0.0, sq = 0.0;
#pragma unroll
    for (int r = 0; r < 8; r++) { sm += s[r * 256]; sq += s[r * 256 + 128]; }
    double mu = sm / n;
    double var = sq / n - mu * mu;
    mu_s[t] = (float)mu;
    inv_s[t] = rsqrtf((float)fmax(var, 0.0) + 1e-4f);
  }
  __syncthreads();
  int total = n * (C / 4);
  for (int gid = blockIdx.x * 256 + t; gid < total; gid += gridDim.x * 256) {
    int i = gid / (C / 4);
    int c = (gid % (C / 4)) * 4;
    int v = list[i];
    float4 xv = *(const float4*)&x[(size_t)v * xstr + coff + c];
    float xa[4] = {xv.x, xv.y, xv.z, xv.w};
    ushort_t u[4];
#pragma unroll
    for (int j = 0; j < 4; j++)
      u[j] = f2bf(fmaxf((xa[j] - mu_s[c + j]) * inv_s[c + j], 0.f));
    uint2 o; o.x = (unsigned)u[0] | ((unsigned)u[1] << 16);
    o.y = (unsigned)u[2] | ((unsigned)u[3] << 16);
    *(uint2*)&out[(size_t)v * C + c] = o;
  }
}

// final BN apply -> dense f32 d_out (zeros at inactive), replica finalize
__global__ __launch_bounds__(256) void k_bnout(const float* __restrict__ x,
                                               const unsigned char* __restrict__ m,
                                               const double* __restrict__ s,
                                               const int* __restrict__ cnt,
                                               float* __restrict__ out) {
  __shared__ float mu_s[32], inv_s[32];
  int t = threadIdx.x;
  int n = cnt[0];
  if (t < 32) {
    double sm = 0.0, sq = 0.0;
#pragma unroll
    for (int r = 0; r < 8; r++) { sm += s[r * 256 + t]; sq += s[r * 256 + 128 + t]; }
    double mu = sm / n;
    double var = sq / n - mu * mu;
    mu_s[t] = (float)mu;
    inv_s[t] = rsqrtf((float)fmax(var, 0.0) + 1e-4f);
  }
  __syncthreads();
  int gid = blockIdx.x * 256 + t;
  if (gid >= N1 * 8) return;
  int v = gid / 8;
  int c = (gid % 8) * 4;
  float4 o = make_float4(0.f, 0.f, 0.f, 0.f);
  if (m[v]) {
    float4 xv = *(const float4*)&x[(size_t)v * 32 + c];
    o.x = fmaxf((xv.x - mu_s[c + 0]) * inv_s[c + 0], 0.f);
    o.y = fmaxf((xv.y - mu_s[c + 1]) * inv_s[c + 1], 0.f);
    o.z = fmaxf((xv.z - mu_s[c + 2]) * inv_s[c + 2], 0.f);
    o.w = fmaxf((xv.w - mu_s[c + 3]) * inv_s[c + 3], 0.f);
  }
  *(float4*)&out[(size_t)v * 32 + c] = o;
}

// 1x1 shortcut: idb[v][o] = sum_c in[v][c] * wsc[o][c]; grid-stride.
template <int CI, int CO>
__global__ __launch_bounds__(256) void k_sc(const float* __restrict__ in,
                                            const float* __restrict__ wsc,
                                            float* __restrict__ out,
                                            const int* __restrict__ list,
                                            const int* __restrict__ cnt) {
  int n = cnt[0];
  long total = (long)n * CO;
  for (long gid = (long)blockIdx.x * 256 + threadIdx.x; gid < total; gid += (long)gridDim.x * 256) {
    int i = (int)(gid / CO), o = (int)(gid % CO);
    int v = list[i];
    const float4* xr = (const float4*)(in + (size_t)v * CI);
    const float4* wr = (const float4*)(wsc + (size_t)o * CI);
    float a = 0.f;
    for (int c = 0; c < CI / 4; c++) {
      float4 x4 = xr[c], w4 = wr[c];
      a += x4.x * w4.x + x4.y * w4.y + x4.z * w4.z + x4.w * w4.w;
    }
    out[(size_t)v * CO + o] = a;
  }
}

// ---------------------------------------------------------------------------
// host launch
// ---------------------------------------------------------------------------
extern "C" void kernel_launch(void* const* d_in, const int* in_sizes, int n_in,
                              void* d_out, int out_size, void* d_ws, size_t ws_size,
                              hipStream_t stream) {
  float* W = (float*)d_ws;
  const float* x = (const float*)d_in[0];

  float* A    = W + OFF_A;
  float* R1   = W + OFF_R1;
  float* CAT1 = W + OFF_CAT1;
  float* D1R  = W + OFF_D1R;
  float* R3   = W + OFF_R3;
  float* CAT2 = W + OFF_CAT2;
  float* D2R  = W + OFF_D2R;
  float* R4   = W + OFF_R4;
  float* X3R  = W + OFF_X3R;
  ushort_t* XP     = (ushort_t*)(W + OFF_CAT1);  // overlay, dead after x0 conv
  ushort_t* BN1_32 = (ushort_t*)(W + OFF_BN1_32);
  ushort_t* BN1_64 = (ushort_t*)(W + OFF_BN1_64);
  ushort_t* BN2A   = (ushort_t*)(W + OFF_BN2_A);
  ushort_t* BN2B   = (ushort_t*)(W + OFF_BN2_B);
  ushort_t* BN3_96 = (ushort_t*)(W + OFF_BN3_96);
  ushort_t* WT  = (ushort_t*)(W + OFF_WT);
  double* S0 = (double*)(W + OFF_STATS);
  int* CNT = (int*)(W + OFF_CNT);
  int* L1 = (int*)(W + OFF_L1);
  int* L2 = (int*)(W + OFF_L2);
  int* L3 = (int*)(W + OFF_L3);
  unsigned char* M1 = (unsigned char*)(W + OFF_M1);
  unsigned char* M2 = (unsigned char*)(W + OFF_M2);
  unsigned char* M3 = (unsigned char*)(W + OFF_M3);

  auto S = [&](int i) { return S0 + (size_t)i * 2048; };
  // slots: 0 x0, 1 b1a, 2 x1, 3 d1, 4 b2a, 5 x2, 6 d2, 7 b3a, 8 x3,
  //        9 u2, 10 h2, 11 t2, 12 u1, 13 h1, 14 t1, 15 dummy

  hipMemsetAsync(W + OFF_STATS, 0, (STATS_FLOATS + 16) * 4, stream);
  hipMemsetAsync(W + OFF_BN1_32, 0, (OFF_BFEND - OFF_BN1_32) * 4, stream);

  k_mask1<<<N1 / 256, 256, 0, stream>>>(x, M1, L1, CNT + 0);
  k_pool<<<N2 / 256, 256, 0, stream>>>(M1, M2, L2, CNT + 1, DIM2);
  k_pool<<<(N3 + 255) / 256, 256, 0, stream>>>(M2, M3, L3, CNT + 2, DIM3);

  WJobs jb;
  const int srcIdx[16]  = {2, 3, 4, 5, 6, 7, 8, 9, 10, 13, 13, 14, 17, 18, 11, 15};
  const short cirtot[16]= {6, 32, 32, 32, 64, 64, 64, 96, 96, 128, 128, 64, 64, 32, 96, 64};
  const short cio[16]   = {0, 0, 0, 0, 0, 0, 0, 0, 0, 0, 64, 0, 0, 0, 0, 0};
  const short cipad[16] = {32, 32, 32, 32, 64, 64, 64, 96, 96, 64, 64, 64, 64, 32, 96, 64};
  const short couts[16] = {32, 32, 32, 64, 64, 64, 96, 96, 96, 64, 64, 64, 32, 32, 64, 32};
  for (int j = 0; j < 16; j++) {
    jb.src[j] = (const float*)d_in[srcIdx[j]];
    jb.cirtot[j] = cirtot[j]; jb.cio[j] = cio[j];
    jb.cipad[j] = cipad[j]; jb.cout[j] = couts[j];
    jb.start[j] = WTS[j];
  }
  jb.start[16] = WTS[16];
  k_wprep<<<(WTS[16] + 255) / 256, 256, 0, stream>>>(jb, WT, WTS[16]);
  k_xprep<<<((N1 + 4) * 8 + 255) / 256, 256, 0, stream>>>(x, XP);

  const int BNG = 512;

  // ---- level 1 down ----
  k_conv12<32, 32, 27, D1, false><<<dim3(448, 1), 512, 0, stream>>>(
      XP, WT + WTS[0], 32, A, 32, 0, nullptr, 0, S(0), L1, CNT + 0);            // x0
  k_bnapply2<32><<<BNG, 256, 0, stream>>>(A, 32, 0, S(0), S(0), 32, L1, CNT + 0, BN1_32);
  k_conv12<32, 32, 27, D1, false><<<dim3(448, 1), 512, 0, stream>>>(
      BN1_32, WT + WTS[1], 32, R1, 32, 0, nullptr, 0, S(1), L1, CNT + 0);       // b1a
  k_bnapply2<32><<<BNG, 256, 0, stream>>>(R1, 32, 0, S(1), S(1), 32, L1, CNT + 0, BN1_32);
  k_conv12<32, 32, 27, D1, false><<<dim3(448, 1), 512, 0, stream>>>(
      BN1_32, WT + WTS[2], 32, CAT1, 64, 0, A, 32, S(2), L1, CNT + 0);          // x1
  k_bnapply2<32><<<BNG, 256, 0, stream>>>(CAT1, 64, 0, S(2), S(2), 32, L1, CNT + 0, BN1_32);
  k_conv12<32, 32, 8, DIM2, false><<<dim3(320, 2), 512, 0, stream>>>(
      BN1_32, WT + WTS[3], 64, D1R, 64, 0, nullptr, 0, S(3), L2, CNT + 1);      // d1

  // ---- level 2 ----
  k_bnapply2<64><<<BNG, 256, 0, stream>>>(D1R, 64, 0, S(3), S(3), 64, L2, CNT + 1, BN2A);
  k_conv12<64, 32, 27, DIM2, false><<<dim3(320, 2), 512, 0, stream>>>(
      BN2A, WT + WTS[4], 64, R3, 64, 0, nullptr, 0, S(4), L2, CNT + 1);         // b2a
  k_bnapply2<64><<<BNG, 256, 0, stream>>>(R3, 64, 0, S(4), S(4), 64, L2, CNT + 1, BN2A);
  k_conv12<64, 32, 27, DIM2, false><<<dim3(320, 2), 512, 0, stream>>>(
      BN2A, WT + WTS[5], 64, CAT2, 128, 0, D1R, 64, S(5), L2, CNT + 1);         // x2
  k_bnapply2<64><<<BNG, 256, 0, stream>>>(CAT2, 128, 0, S(5), S(5), 64, L2, CNT + 1, BN2A);
  k_conv12<64, 32, 8, DIM3, false><<<dim3(108, 3), 512, 0, stream>>>(
      BN2A, WT + WTS[6], 96, D2R, 96, 0, nullptr, 0, S(6), L3, CNT + 2);        // d2

  // ---- level 3 ----
  k_bnapply2<96><<<BNG, 256, 0, stream>>>(D2R, 96, 0, S(6), S(6), 96, L3, CNT + 2, BN3_96);
  k_conv12<96, 16, 27, DIM3, false><<<dim3(108, 6), 512, 0, stream>>>(
      BN3_96, WT + WTS[7], 96, R4, 96, 0, nullptr, 0, S(7), L3, CNT + 2);       // b3a
  k_bnapply2<96><<<BNG, 256, 0, stream>>>(R4, 96, 0, S(7), S(7), 96, L3, CNT + 2, BN3_96);
  k_conv12<96, 16, 27, DIM3, false><<<dim3(108, 6), 512, 0, stream>>>(
      BN3_96, WT + WTS[8], 96, X3R, 96, 0, D2R, 96, S(8), L3, CNT + 2);         // x3
  k_bnapply2<96><<<BNG, 256, 0, stream>>>(X3R, 96, 0, S(8), S(8), 96, L3, CNT + 2, BN3_96);
  k_conv12<96, 32, 8, DIM2, true><<<dim3(320, 2), 512, 0, stream>>>(
      BN3_96, WT + WTS[14], 64, CAT2, 128, 64, nullptr, 0, S(9), L2, CNT + 1);  // u2

  // ---- tail level 2 (h2 split into two 64-ci halves) ----
  k_bnapply2<64><<<BNG, 256, 0, stream>>>(CAT2, 128, 64, S(9), S(9), 64, L2, CNT + 1, BN2B);
  k_conv12<64, 32, 27, DIM2, false><<<dim3(320, 2), 512, 0, stream>>>(
      BN2A, WT + WTS[9], 64, R3, 64, 0, nullptr, 0, S(15), L2, CNT + 1);        // h2A
  k_conv12<64, 32, 27, DIM2, false><<<dim3(320, 2), 512, 0, stream>>>(
      BN2B, WT + WTS[10], 64, R3, 64, 0, R3, 64, S(10), L2, CNT + 1);           // h2B (+res)
  k_bnapply2<64><<<BNG, 256, 0, stream>>>(R3, 64, 0, S(10), S(10), 64, L2, CNT + 1, BN2A);
  k_sc<128, 64><<<512, 256, 0, stream>>>(CAT2, (const float*)d_in[12], D1R, L2, CNT + 1);
  k_conv12<64, 32, 27, DIM2, false><<<dim3(320, 2), 512, 0, stream>>>(
      BN2A, WT + WTS[11], 64, R3, 64, 0, D1R, 64, S(11), L2, CNT + 1);          // t2
  k_bnapply2<64><<<BNG, 256, 0, stream>>>(R3, 64, 0, S(11), S(11), 64, L2, CNT + 1, BN2A);
  k_conv12<64, 32, 8, D1, true><<<dim3(448, 1), 512, 0, stream>>>(
      BN2A, WT + WTS[15], 32, CAT1, 64, 32, nullptr, 0, S(12), L1, CNT + 0);    // u1

  // ---- tail level 1 ----
  k_bnapply2<64><<<BNG, 256, 0, stream>>>(CAT1, 64, 0, S(2), S(12), 32, L1, CNT + 0, BN1_64);
  k_conv12<64, 32, 27, D1, false><<<dim3(448, 1), 512, 0, stream>>>(
      BN1_64, WT + WTS[12], 32, R1, 32, 0, nullptr, 0, S(13), L1, CNT + 0);     // h1
  k_bnapply2<32><<<BNG, 256, 0, stream>>>(R1, 32, 0, S(13), S(13), 32, L1, CNT + 0, BN1_32);
  k_sc<64, 32><<<512, 256, 0, stream>>>(CAT1, (const float*)d_in[16], A, L1, CNT + 0);
  k_conv12<32, 32, 27, D1, false><<<dim3(448, 1), 512, 0, stream>>>(
      BN1_32, WT + WTS[13], 32, A, 32, 0, A, 32, S(14), L1, CNT + 0);           // t1
  k_bnout<<<N1 * 8 / 256, 256, 0, stream>>>(A, M1, S(14), CNT + 0, (float*)d_out);
}